// Round 3
// baseline (69.465 us; speedup 1.0000x reference)
//
#include <hip/hip_runtime.h>

constexpr int M_ROWS = 16000;   // B*T
constexpr int DIM    = 512;
constexpr int NEXP   = 10;
constexpr int NSH    = 5;
constexpr int KTOP   = 5;

constexpr int TM = 64;          // rows per block
constexpr int BK = 32;          // k-tile

typedef __attribute__((ext_vector_type(8))) short  bf16x8;
typedef __attribute__((ext_vector_type(4))) float  f32x4;

__device__ inline unsigned short bf16_rne(float x) {
    unsigned u = __float_as_uint(x);
    u += 0x7fffu + ((u >> 16) & 1u);
    return (unsigned short)(u >> 16);
}
__device__ inline float bf16_to_f(unsigned short h) {
    return __uint_as_float(((unsigned)h) << 16);
}

// ---------------- prep: W1 -> (hi,lo) bf16 [N][K]; shsum = sum_s shared_w ----
__global__ __launch_bounds__(256)
void prep_kernel(const float* __restrict__ W1, const float* __restrict__ shared_w,
                 unsigned short* __restrict__ w1hi, unsigned short* __restrict__ w1lo,
                 float* __restrict__ shsum)
{
    int b = blockIdx.x;
    if (b < 256) {
        int f = b * 256 + threadIdx.x;          // 0..65535, 4 floats each
        float4 v = *reinterpret_cast<const float4*>(&W1[(size_t)f * 4]);
        float xs[4] = {v.x, v.y, v.z, v.w};
        ushort4 h4, l4;
        unsigned short h[4], l[4];
        #pragma unroll
        for (int i = 0; i < 4; ++i) {
            h[i] = bf16_rne(xs[i]);
            float rem = xs[i] - bf16_to_f(h[i]);   // exact in fp32
            l[i] = bf16_rne(rem);
        }
        h4.x = h[0]; h4.y = h[1]; h4.z = h[2]; h4.w = h[3];
        l4.x = l[0]; l4.y = l[1]; l4.z = l[2]; l4.w = l[3];
        *reinterpret_cast<ushort4*>(&w1hi[(size_t)f * 4]) = h4;
        *reinterpret_cast<ushort4*>(&w1lo[(size_t)f * 4]) = l4;
    } else {
        for (int c = threadIdx.x; c < DIM; c += 256) {
            float s = 0.f;
            #pragma unroll
            for (int e = 0; e < NSH; ++e) s += shared_w[e * DIM + c];
            shsum[c] = s;
        }
    }
}

// ---------------- main fused kernel ----------------
// Block: 64 rows x 512 cols, 512 threads = 8 waves.
// Wave wv owns ALL 64 rows x cols [wv*64, wv*64+64): acc[4 rt][4 ct] of 16x16.
// LDS (shorts):
//   Bbuf[2] @ 0, 32768      : each = hi[512][32] (16384) + lo[512][32] (16384)
//   Abuf[2] @ 65536, 69632  : each = hi[64][32] (2048)  + lo[64][32] (2048)
// Chunk swizzle (16B chunks within a 64B row): phys = logical ^ ((row>>1)&3),
// applied on the gload_lds SOURCE (B), on the ds_write column (A), and on all
// fragment reads -> uniform 2-way bank aliasing (free).
__global__ __launch_bounds__(512, 2)
void moe_mfma(const float* __restrict__ G, const float* __restrict__ value,
              const float* __restrict__ routing_w, const float* __restrict__ W2,
              const unsigned short* __restrict__ w1hi, const unsigned short* __restrict__ w1lo,
              const float* __restrict__ shsum, float* __restrict__ out)
{
    __shared__ unsigned short smem[73728];   // 147456 B

    const int tid  = threadIdx.x;
    const int lane = tid & 63;
    const int wv   = tid >> 6;          // 0..7 = col-slice
    const int l15  = lane & 15;
    const int lg   = lane >> 4;         // 0..3
    const int row0 = blockIdx.x * TM;

    const int arow = tid >> 3;          // 0..63 (A-stage row)
    const int aq   = tid & 7;           // 0..7  (A-stage float4 slot)
    const int as   = (arow >> 1) & 3;   // A-row swizzle key
    const int acol = ((aq >> 1) ^ as) * 8 + (aq & 1) * 4;  // swizzled short offset

    f32x4 acc[4][4];
    #pragma unroll
    for (int rt = 0; rt < 4; ++rt)
        #pragma unroll
        for (int ct = 0; ct < 4; ++ct) acc[rt][ct] = (f32x4)0.f;

    // ---- staging helpers
    auto stageB = [&](int k0, int buf) {
        unsigned short* bb = smem + buf * 32768;
        #pragma unroll
        for (int r = 0; r < 4; ++r) {
            int f = r * 512 + tid;       // 0..2047
            int n = f >> 2;              // col 0..511
            int j = f & 3;               // phys chunk
            int js = j ^ ((n >> 1) & 3); // logical chunk at this phys slot
            __builtin_amdgcn_global_load_lds(
                (const __attribute__((address_space(1))) void*)(w1hi + (size_t)n * DIM + k0 + js * 8),
                (__attribute__((address_space(3))) void*)(bb + f * 8), 16, 0, 0);
        }
        #pragma unroll
        for (int r = 0; r < 4; ++r) {
            int f = r * 512 + tid;
            int n = f >> 2;
            int j = f & 3;
            int js = j ^ ((n >> 1) & 3);
            __builtin_amdgcn_global_load_lds(
                (const __attribute__((address_space(1))) void*)(w1lo + (size_t)n * DIM + k0 + js * 8),
                (__attribute__((address_space(3))) void*)(bb + 16384 + f * 8), 16, 0, 0);
        }
    };
    auto writeA = [&](int buf, float4 g4) {
        unsigned short* ab = smem + 65536 + buf * 4096;
        float xs[4] = {g4.x, g4.y, g4.z, g4.w};
        unsigned short h[4], l[4];
        #pragma unroll
        for (int i = 0; i < 4; ++i) {
            h[i] = bf16_rne(xs[i]);
            float rem = xs[i] - bf16_to_f(h[i]);
            l[i] = bf16_rne(rem);
        }
        ushort4 h4, l4;
        h4.x = h[0]; h4.y = h[1]; h4.z = h[2]; h4.w = h[3];
        l4.x = l[0]; l4.y = l[1]; l4.z = l[2]; l4.w = l[3];
        *reinterpret_cast<ushort4*>(&ab[arow * 32 + acol])        = h4;
        *reinterpret_cast<ushort4*>(&ab[2048 + arow * 32 + acol]) = l4;
    };

    // ---- prologue: stage tile 0
    {
        float4 g4 = *reinterpret_cast<const float4*>(&G[(size_t)(row0 + arow) * DIM + aq * 4]);
        stageB(0, 0);
        writeA(0, g4);
    }
    __syncthreads();

    // ---- 2-phase pipelined K loop
    for (int t = 0; t < DIM / BK; ++t) {
        const int cur = t & 1;
        unsigned short* bb = smem + cur * 32768;
        unsigned short* ab = smem + 65536 + cur * 4096;

        float4 g4;
        const bool pre = (t + 1 < DIM / BK);
        if (pre) {
            g4 = *reinterpret_cast<const float4*>(
                     &G[(size_t)(row0 + arow) * DIM + (t + 1) * BK + aq * 4]);
            stageB((t + 1) * BK, cur ^ 1);
        }

        // A fragments (hi/lo) for the 4 row-tiles
        bf16x8 ah[4], al[4];
        #pragma unroll
        for (int rt = 0; rt < 4; ++rt) {
            int r_ = rt * 16 + l15;
            int cs = (lg ^ ((r_ >> 1) & 3)) * 8;
            ah[rt] = *reinterpret_cast<const bf16x8*>(&ab[r_ * 32 + cs]);
            al[rt] = *reinterpret_cast<const bf16x8*>(&ab[2048 + r_ * 32 + cs]);
        }
        // B fragments + MFMA
        #pragma unroll
        for (int ct = 0; ct < 4; ++ct) {
            int n  = wv * 64 + ct * 16 + l15;
            int cs = (lg ^ ((n >> 1) & 3)) * 8;
            bf16x8 bh = *reinterpret_cast<const bf16x8*>(&bb[n * 32 + cs]);
            bf16x8 bl = *reinterpret_cast<const bf16x8*>(&bb[16384 + n * 32 + cs]);
            #pragma unroll
            for (int rt = 0; rt < 4; ++rt) {
                acc[rt][ct] = __builtin_amdgcn_mfma_f32_16x16x32_bf16(ah[rt], bh, acc[rt][ct], 0, 0, 0);
                acc[rt][ct] = __builtin_amdgcn_mfma_f32_16x16x32_bf16(ah[rt], bl, acc[rt][ct], 0, 0, 0);
                acc[rt][ct] = __builtin_amdgcn_mfma_f32_16x16x32_bf16(al[rt], bh, acc[rt][ct], 0, 0, 0);
            }
        }
        if (pre) writeA(cur ^ 1, g4);
        __syncthreads();
    }

    // ---- ReLU
    #pragma unroll
    for (int rt = 0; rt < 4; ++rt)
        #pragma unroll
        for (int ct = 0; ct < 4; ++ct)
            #pragma unroll
            for (int j = 0; j < 4; ++j)
                acc[rt][ct][j] = fmaxf(acc[rt][ct][j], 0.f);

    // ---- per-wave logit partials (each wave covers its 64 cols)
    float* plog = reinterpret_cast<float*>(smem);        // [8][64][10]
    float* swls = reinterpret_cast<float*>(smem) + 5120; // [64][10]

    #pragma unroll
    for (int e = 0; e < NEXP; ++e) {
        float w2v[4];
        #pragma unroll
        for (int ct = 0; ct < 4; ++ct)
            w2v[ct] = W2[(size_t)e * DIM + wv * 64 + ct * 16 + l15];
        #pragma unroll
        for (int rt = 0; rt < 4; ++rt) {
            #pragma unroll
            for (int j = 0; j < 4; ++j) {
                float s = 0.f;
                #pragma unroll
                for (int ct = 0; ct < 4; ++ct)
                    s = fmaf(acc[rt][ct][j], w2v[ct], s);
                s += __shfl_xor(s, 1, 16);
                s += __shfl_xor(s, 2, 16);
                s += __shfl_xor(s, 4, 16);
                s += __shfl_xor(s, 8, 16);
                if (l15 == 0)
                    plog[(wv * TM + rt * 16 + lg * 4 + j) * NEXP + e] = s;
            }
        }
    }
    __syncthreads();

    // ---- cross-wave reduce + softmax + top-5 (one thread per row)
    if (tid < TM) {
        float lgt[NEXP];
        #pragma unroll
        for (int e = 0; e < NEXP; ++e) {
            float s = 0.f;
            #pragma unroll
            for (int w = 0; w < 8; ++w) s += plog[(w * TM + tid) * NEXP + e];
            lgt[e] = s;
        }
        float mx = lgt[0];
        #pragma unroll
        for (int e = 1; e < NEXP; ++e) mx = fmaxf(mx, lgt[e]);
        float p[NEXP], se = 0.f;
        #pragma unroll
        for (int e = 0; e < NEXP; ++e) { p[e] = expf(lgt[e] - mx); se += p[e]; }
        float inv = 1.f / se;
        #pragma unroll
        for (int e = 0; e < NEXP; ++e) p[e] *= inv;
        unsigned used = 0;
        #pragma unroll
        for (int t = 0; t < KTOP; ++t) {
            float bv = -1.f; int bi = 0;
            #pragma unroll
            for (int e = 0; e < NEXP; ++e) {
                bool better = (((used >> e) & 1u) == 0u) && (p[e] > bv);
                bv = better ? p[e] : bv;
                bi = better ? e : bi;
            }
            used |= 1u << bi;
        }
        #pragma unroll
        for (int e = 0; e < NEXP; ++e)
            swls[tid * NEXP + e] = ((used >> e) & 1u) ? p[e] : 0.f;
    }
    __syncthreads();

    // ---- output: out[row][col] = value[row]*(shsum[col] + sum_e sw[e]*rw[e][col])
    const int c4 = (tid & 127) * 4;
    const int rh = tid >> 7;                       // 0..3 -> rows rh*16..+15
    float4 sh4 = *reinterpret_cast<const float4*>(&shsum[c4]);
    float4 rw4[NEXP];
    #pragma unroll
    for (int e = 0; e < NEXP; ++e)
        rw4[e] = *reinterpret_cast<const float4*>(&routing_w[(size_t)e * DIM + c4]);
    #pragma unroll
    for (int r = 0; r < 16; ++r) {
        int row = rh * 16 + r;
        float val = value[row0 + row];
        float4 o = sh4;
        #pragma unroll
        for (int e = 0; e < NEXP; ++e) {
            float wgt = swls[row * NEXP + e];
            o.x = fmaf(wgt, rw4[e].x, o.x);
            o.y = fmaf(wgt, rw4[e].y, o.y);
            o.z = fmaf(wgt, rw4[e].z, o.z);
            o.w = fmaf(wgt, rw4[e].w, o.w);
        }
        o.x *= val; o.y *= val; o.z *= val; o.w *= val;
        *reinterpret_cast<float4*>(&out[(size_t)(row0 + row) * DIM + c4]) = o;
    }
}

extern "C" void kernel_launch(void* const* d_in, const int* in_sizes, int n_in,
                              void* d_out, int out_size, void* d_ws, size_t ws_size,
                              hipStream_t stream) {
    const float* G         = (const float*)d_in[0];
    const float* value     = (const float*)d_in[1];
    const float* shared_w  = (const float*)d_in[2];
    const float* routing_w = (const float*)d_in[3];
    const float* W1        = (const float*)d_in[4];
    const float* W2        = (const float*)d_in[5];
    float* out             = (float*)d_out;

    unsigned short* w1hi = (unsigned short*)d_ws;                       // 512 KB
    unsigned short* w1lo = (unsigned short*)((char*)d_ws + 524288);     // 512 KB
    float*          shs  = (float*)((char*)d_ws + 1048576);             // 2 KB

    prep_kernel<<<257, 256, 0, stream>>>(W1, shared_w, w1hi, w1lo, shs);
    moe_mfma<<<M_ROWS / TM, 512, 0, stream>>>(G, value, routing_w, W2,
                                              w1hi, w1lo, shs, out);
}